// Round 1
// 2504.994 us; speedup vs baseline: 1.0722x; 1.0722x over previous
//
#include <hip/hip_runtime.h>
#include <stdint.h>

typedef _Float16 f16;
typedef f16 f16x8 __attribute__((ext_vector_type(8)));
typedef f16 f16x4 __attribute__((ext_vector_type(4)));
typedef float f32x4 __attribute__((ext_vector_type(4)));

#define N_KEYS   50000
#define N_KEYS_P 50048
#define BATCH    2048
#define EDIM     3072
#define CAP      256
#define TAU      0.052f

// ---------------- reduction helpers ----------------
__device__ __forceinline__ float wred(float v) {
#pragma unroll
  for (int o = 32; o > 0; o >>= 1) v += __shfl_xor(v, o);
  return v;
}
__device__ __forceinline__ double wredd(double v) {
#pragma unroll
  for (int o = 32; o > 0; o >>= 1) v += __shfl_xor(v, o);
  return v;
}
__device__ __forceinline__ float bredf(float v, float* red) {
  v = wred(v);
  __syncthreads();
  if ((threadIdx.x & 63) == 0) red[threadIdx.x >> 6] = v;
  __syncthreads();
  return red[0] + red[1] + red[2] + red[3];
}
__device__ __forceinline__ double bredd(double v, double* red) {
  v = wredd(v);
  __syncthreads();
  if ((threadIdx.x & 63) == 0) red[threadIdx.x >> 6] = v;
  __syncthreads();
  return red[0] + red[1] + red[2] + red[3];
}

__device__ __forceinline__ void gll16(const void* g, void* l) {
  __builtin_amdgcn_global_load_lds((const __attribute__((address_space(1))) void*)g,
                                   (__attribute__((address_space(3))) void*)l, 16, 0, 0);
}

// ---------------- keys: f64 row norms + fp16 normalized copy ----------------
__global__ __launch_bounds__(256) void rownorm_keys(const float* __restrict__ keys,
                                                    f16* __restrict__ kn16,
                                                    double* __restrict__ inv_norm) {
  int n = blockIdx.x;
  int t = threadIdx.x;
  __shared__ double red[4];
  __shared__ double bc;
  f16* dst = kn16 + (size_t)n * EDIM;
  if (n >= N_KEYS) {  // zero pad rows so GEMM OOB columns read zeros
    f16x4 z = {(f16)0.f, (f16)0.f, (f16)0.f, (f16)0.f};
    for (int i = 0; i < 3; i++) *(f16x4*)(dst + (size_t)(t + 256 * i) * 4) = z;
    if (t == 0) inv_norm[n] = 0.0;
    return;  // block-uniform branch
  }
  const float4* src = (const float4*)(keys + (size_t)n * EDIM);
  float4 v[3];
  double s = 0.0;
#pragma unroll
  for (int i = 0; i < 3; i++) {
    v[i] = src[t + 256 * i];
    s += (double)v[i].x * (double)v[i].x + (double)v[i].y * (double)v[i].y +
         (double)v[i].z * (double)v[i].z + (double)v[i].w * (double)v[i].w;
  }
  s = bredd(s, red);
  if (t == 0) {
    double nrm = sqrt(s);
    double inv = 1.0 / fmax(nrm, 1e-12);
    inv_norm[n] = inv;
    bc = inv;
  }
  __syncthreads();
  float inv = (float)bc;
#pragma unroll
  for (int i = 0; i < 3; i++) {
    f16x4 h = {(f16)(v[i].x * inv), (f16)(v[i].y * inv), (f16)(v[i].z * inv), (f16)(v[i].w * inv)};
    *(f16x4*)(dst + (size_t)(t + 256 * i) * 4) = h;
  }
}

// ---------------- generic f32 -> f16 convert ----------------
__global__ __launch_bounds__(256) void cvt_f16(const float* __restrict__ src, f16* __restrict__ dst, int n) {
  int i = blockIdx.x * 256 + threadIdx.x;
  if (i < n) dst[i] = (f16)src[i];
}

// ---------------- fp32 GEMM: C = act(A @ W^T + bias); optional f64 chunk accumulation ----------------
template <int DACC, int RELU>
__global__ __launch_bounds__(256) void gemm_f32(const float* __restrict__ A, int lda,
                                                const float* __restrict__ W,
                                                const float* __restrict__ bias,
                                                float* __restrict__ C, int ldc, int K) {
  __shared__ alignas(16) float As[64][20];
  __shared__ alignas(16) float Ws[64][20];
  int t = threadIdx.x;
  int tx = t & 15, ty = t >> 4;
  int m0 = blockIdx.x * 64, n0 = blockIdx.y * 64;
  float accf[4][4];
  double accd[4][4];
#pragma unroll
  for (int r = 0; r < 4; r++)
#pragma unroll
    for (int c = 0; c < 4; c++) { accf[r][c] = 0.f; accd[r][c] = 0.0; }
  for (int k0 = 0; k0 < K; k0 += 16) {
#pragma unroll
    for (int i = 0; i < 4; i++) {
      int e = t + 256 * i;
      int r = e >> 4, cc = e & 15;
      int kk = k0 + cc;
      As[r][cc] = (kk < K) ? A[(size_t)(m0 + r) * lda + kk] : 0.f;
      Ws[r][cc] = (kk < K) ? W[(size_t)(n0 + r) * K + kk] : 0.f;
    }
    __syncthreads();
    float chunk[4][4];
#pragma unroll
    for (int r = 0; r < 4; r++)
#pragma unroll
      for (int c = 0; c < 4; c++) chunk[r][c] = 0.f;
#pragma unroll
    for (int kk4 = 0; kk4 < 16; kk4 += 4) {
      float4 a[4], w[4];
#pragma unroll
      for (int r = 0; r < 4; r++) a[r] = *(const float4*)&As[ty * 4 + r][kk4];
#pragma unroll
      for (int c = 0; c < 4; c++) w[c] = *(const float4*)&Ws[tx * 4 + c][kk4];
#pragma unroll
      for (int r = 0; r < 4; r++)
#pragma unroll
        for (int c = 0; c < 4; c++)
          chunk[r][c] += a[r].x * w[c].x + a[r].y * w[c].y + a[r].z * w[c].z + a[r].w * w[c].w;
    }
    if constexpr (DACC) {
#pragma unroll
      for (int r = 0; r < 4; r++)
#pragma unroll
        for (int c = 0; c < 4; c++) accd[r][c] += (double)chunk[r][c];
    } else {
#pragma unroll
      for (int r = 0; r < 4; r++)
#pragma unroll
        for (int c = 0; c < 4; c++) accf[r][c] += chunk[r][c];
    }
    __syncthreads();
  }
#pragma unroll
  for (int r = 0; r < 4; r++)
#pragma unroll
    for (int c = 0; c < 4; c++) {
      int row = m0 + ty * 4 + r, col = n0 + tx * 4 + c;
      float v;
      if constexpr (DACC) v = (float)(accd[r][c] + (double)bias[col]);
      else v = accf[r][c] + bias[col];
      if constexpr (RELU) v = fmaxf(v, 0.f);
      C[(size_t)row * ldc + col] = v;
    }
}

// ---------------- fp16 MFMA GEMM, 128x128 tile, 16x16x32 MFMA (small shapes) ----------------
// MODE 0: C32 = act(acc+bias); MODE 1: C16 = act(acc+bias); MODE 2: scores epilogue (threshold append)
template <int MODE, int RELU>
__global__ __launch_bounds__(256) void gemm_f16k(const f16* __restrict__ A, int lda,
                                                 const f16* __restrict__ W,  // N x K
                                                 const float* __restrict__ bias,
                                                 float* __restrict__ C32, f16* __restrict__ C16,
                                                 int ldc, int col_off, int K, int Nreal,
                                                 float* __restrict__ cand_s, int* __restrict__ cand_i,
                                                 int* __restrict__ cand_cnt) {
  __shared__ alignas(16) f16 As[128 * 32];
  __shared__ alignas(16) f16 Bs[128 * 32];
  int t = threadIdx.x;
  int wave = t >> 6, lane = t & 63;
  int wm = wave >> 1, wn = wave & 1;
  int m0 = blockIdx.x * 128, n0 = blockIdx.y * 128;
  f32x4 acc[4][4];
#pragma unroll
  for (int i = 0; i < 4; i++)
#pragma unroll
    for (int j = 0; j < 4; j++) acc[i][j] = (f32x4){0.f, 0.f, 0.f, 0.f};

  for (int k0 = 0; k0 < K; k0 += 32) {
#pragma unroll
    for (int i = 0; i < 2; i++) {
      int c = i * 256 + wave * 64 + lane;
      int r = c >> 2;
      int kof = (c & 3) * 8;
      const f16* gA = A + (size_t)(m0 + r) * lda + k0 + kof;
      const f16* gB = W + (size_t)(n0 + r) * K + k0 + kof;
      f16* lA = As + (size_t)(i * 256 + wave * 64) * 8;
      f16* lB = Bs + (size_t)(i * 256 + wave * 64) * 8;
      gll16(gA, lA);
      gll16(gB, lB);
    }
    __syncthreads();
    f16x8 af[4], bf[4];
#pragma unroll
    for (int mi = 0; mi < 4; mi++)
      af[mi] = *(const f16x8*)&As[(wm * 64 + mi * 16 + (lane & 15)) * 32 + (lane >> 4) * 8];
#pragma unroll
    for (int ni = 0; ni < 4; ni++)
      bf[ni] = *(const f16x8*)&Bs[(wn * 64 + ni * 16 + (lane & 15)) * 32 + (lane >> 4) * 8];
#pragma unroll
    for (int mi = 0; mi < 4; mi++)
#pragma unroll
      for (int ni = 0; ni < 4; ni++)
        acc[mi][ni] = __builtin_amdgcn_mfma_f32_16x16x32_f16(af[mi], bf[ni], acc[mi][ni], 0, 0, 0);
    __syncthreads();
  }

  int colq = lane & 15, rq = lane >> 4;
#pragma unroll
  for (int mi = 0; mi < 4; mi++) {
#pragma unroll
    for (int ni = 0; ni < 4; ni++) {
      int col = n0 + wn * 64 + ni * 16 + colq;
      int row0 = m0 + wm * 64 + mi * 16 + rq * 4;
#pragma unroll
      for (int r = 0; r < 4; r++) {
        float v = acc[mi][ni][r];
        int row = row0 + r;
        if constexpr (MODE == 2) {
          if (col < Nreal && v > TAU) {
            int p = atomicAdd(&cand_cnt[row], 1);
            if (p < CAP) {
              cand_s[row * CAP + p] = v;
              cand_i[row * CAP + p] = col;
            }
          }
        } else {
          v += bias[col];
          if constexpr (RELU) v = fmaxf(v, 0.f);
          if constexpr (MODE == 0) C32[(size_t)row * ldc + col + col_off] = v;
          if constexpr (MODE == 1) C16[(size_t)row * ldc + col + col_off] = (f16)v;
        }
      }
    }
  }
}

// =============================================================================
// 256x256-tile 8-phase fp16 MFMA GEMM (T2 swizzle + T3/T4 counted vmcnt + T5 setprio).
// 512 threads = 8 waves (2M x 4N); per-wave C = 128x64. BK=64, split in two 256x32 K-half
// slabs per matrix per buffer; 2 K-tile buffers => 128 KiB LDS.
// Requires K % 64 == 0 and K >= 128. M % 256 == 0. Grid: (M/256, ceil(N/256)).
// LDS swizzle: byte ^= (row&7)<<4 (2-way bank alias = free). global_load_lds writes
// linearly, so the per-lane GLOBAL source address is pre-permuted with the inverse map.
// MODE 1: C16 = act(acc+bias); MODE 2: scores threshold-append epilogue.
// Accumulation order (k ascending per fragment) is identical to gemm_f16k => bit-identical.
template <int MODE, int RELU>
__global__ __launch_bounds__(512, 2) void gemm256(const f16* __restrict__ A, int lda,
                                                  const f16* __restrict__ W,  // N x K
                                                  const float* __restrict__ bias,
                                                  f16* __restrict__ C16, int ldc,
                                                  int K, int Nreal,
                                                  float* __restrict__ cand_s, int* __restrict__ cand_i,
                                                  int* __restrict__ cand_cnt) {
  __shared__ alignas(16) f16 sm[2][2][2][8192];  // [buf][A=0/B=1][khalf][256*32]
  const int t = threadIdx.x;
  const int wave = t >> 6, lane = t & 63;
  const int wm = wave >> 2, wn = wave & 3;
  const int r15 = lane & 15, q = lane >> 4;
  const int m0 = blockIdx.x * 256, n0 = blockIdx.y * 256;
  const int NT = K >> 6;

  // inverse-swizzle source coords: linear LDS granule g holds logical (r_l, cg_l)
  // with pos(r,cg) = (r*4+cg) ^ (r&7); inverse: r = 2*(g>>3) + ((g>>2 ^ g>>4)&1), cg = (g&3)^(r&3)
  const int g0 = t, g1 = 512 + t;
  const int r0 = 2 * (g0 >> 3) + (((g0 >> 2) ^ (g0 >> 4)) & 1);
  const int c0 = (g0 & 3) ^ (r0 & 3);
  const int r1 = 2 * (g1 >> 3) + (((g1 >> 2) ^ (g1 >> 4)) & 1);
  const int c1 = (g1 & 3) ^ (r1 & 3);
  const f16* gA0 = A + (size_t)(m0 + r0) * lda + c0 * 8;
  const f16* gA1 = A + (size_t)(m0 + r1) * lda + c1 * 8;
  const f16* gB0 = W + (size_t)(n0 + r0) * K + c0 * 8;
  const f16* gB1 = W + (size_t)(n0 + r1) * K + c1 * 8;
  const int ldsw0 = wave * 64 * 8;          // wave-uniform LDS dest, f16 units (i=0)
  const int ldsw1 = (512 + wave * 64) * 8;  // (i=1)

  // swizzled ds_read offsets (f16 units); +mi*512 walks 16-row fragments (swizzle invariant)
  const int aoff = ((wm * 128 + r15) * 32 + q * 8) ^ ((r15 & 7) << 3);
  const int boff = ((wn * 64 + r15) * 32 + q * 8) ^ ((r15 & 7) << 3);

  f32x4 acc[8][4];
#pragma unroll
  for (int i = 0; i < 8; i++)
#pragma unroll
    for (int j = 0; j < 4; j++) acc[i][j] = (f32x4){0.f, 0.f, 0.f, 0.f};

#define STAGE_A(bb, kk, ts)                          \
  {                                                  \
    f16* slab_ = &sm[(bb)][0][(kk)][0];              \
    int ko_ = (ts) * 64 + (kk) * 32;                 \
    gll16(gA0 + ko_, slab_ + ldsw0);                 \
    gll16(gA1 + ko_, slab_ + ldsw1);                 \
  }
#define STAGE_B(bb, kk, ts)                          \
  {                                                  \
    f16* slab_ = &sm[(bb)][1][(kk)][0];              \
    int ko_ = (ts) * 64 + (kk) * 32;                 \
    gll16(gB0 + ko_, slab_ + ldsw0);                 \
    gll16(gB1 + ko_, slab_ + ldsw1);                 \
  }

  // prologue: tile0 fully + tile1's kh0 pair; then wait oldest 4 stages (tile0)
  STAGE_A(0, 0, 0); STAGE_B(0, 0, 0);
  STAGE_A(0, 1, 0); STAGE_B(0, 1, 0);
  STAGE_A(1, 0, 1); STAGE_B(1, 0, 1);
  asm volatile("s_waitcnt vmcnt(4)" ::: "memory");
  __builtin_amdgcn_s_barrier();

  for (int tt = 0; tt < NT; ++tt) {
    __builtin_amdgcn_sched_barrier(0);  // pin: no ds_read hoists above the tile-start barrier
    const int buf = tt & 1;
    const f16* A0s = &sm[buf][0][0][0];
    const f16* A1s = &sm[buf][0][1][0];
    const f16* B0s = &sm[buf][1][0][0];
    const f16* B1s = &sm[buf][1][1][0];
    f16x8 af[4], bf[4];

    // ---- P1: kh0, acc rows 0-3 ----
#pragma unroll
    for (int i = 0; i < 4; i++) af[i] = *(const f16x8*)&A0s[aoff + i * 512];
#pragma unroll
    for (int i = 0; i < 4; i++) bf[i] = *(const f16x8*)&B0s[boff + i * 512];
    if (tt + 1 < NT) STAGE_A(buf ^ 1, 1, tt + 1);
    __builtin_amdgcn_s_barrier();
    __builtin_amdgcn_s_setprio(1);
#pragma unroll
    for (int mi = 0; mi < 4; mi++)
#pragma unroll
      for (int ni = 0; ni < 4; ni++)
        acc[mi][ni] = __builtin_amdgcn_mfma_f32_16x16x32_f16(af[mi], bf[ni], acc[mi][ni], 0, 0, 0);
    __builtin_amdgcn_s_setprio(0);
    __builtin_amdgcn_s_barrier();

    // ---- P2: kh0, acc rows 4-7 (reuse bf) ----
#pragma unroll
    for (int i = 0; i < 4; i++) af[i] = *(const f16x8*)&A0s[aoff + (4 + i) * 512];
    if (tt + 1 < NT) STAGE_B(buf ^ 1, 1, tt + 1);
    __builtin_amdgcn_s_barrier();
    __builtin_amdgcn_s_setprio(1);
#pragma unroll
    for (int mi = 0; mi < 4; mi++)
#pragma unroll
      for (int ni = 0; ni < 4; ni++)
        acc[4 + mi][ni] = __builtin_amdgcn_mfma_f32_16x16x32_f16(af[mi], bf[ni], acc[4 + mi][ni], 0, 0, 0);
    __builtin_amdgcn_s_setprio(0);
    __builtin_amdgcn_s_barrier();

    // ---- P3: kh1, acc rows 0-3; kh0 slabs of this buf are dead -> prefetch tile t+2 ----
#pragma unroll
    for (int i = 0; i < 4; i++) af[i] = *(const f16x8*)&A1s[aoff + i * 512];
#pragma unroll
    for (int i = 0; i < 4; i++) bf[i] = *(const f16x8*)&B1s[boff + i * 512];
    if (tt + 2 < NT) STAGE_A(buf, 0, tt + 2);
    __builtin_amdgcn_s_barrier();
    __builtin_amdgcn_s_setprio(1);
#pragma unroll
    for (int mi = 0; mi < 4; mi++)
#pragma unroll
      for (int ni = 0; ni < 4; ni++)
        acc[mi][ni] = __builtin_amdgcn_mfma_f32_16x16x32_f16(af[mi], bf[ni], acc[mi][ni], 0, 0, 0);
    __builtin_amdgcn_s_setprio(0);
    __builtin_amdgcn_s_barrier();

    // ---- P4: kh1, acc rows 4-7; tile-end counted wait (never 0 in steady state) ----
#pragma unroll
    for (int i = 0; i < 4; i++) af[i] = *(const f16x8*)&A1s[aoff + (4 + i) * 512];
    if (tt + 2 < NT) STAGE_B(buf, 0, tt + 2);
    __builtin_amdgcn_s_barrier();
    __builtin_amdgcn_s_setprio(1);
#pragma unroll
    for (int mi = 0; mi < 4; mi++)
#pragma unroll
      for (int ni = 0; ni < 4; ni++)
        acc[4 + mi][ni] = __builtin_amdgcn_mfma_f32_16x16x32_f16(af[mi], bf[ni], acc[4 + mi][ni], 0, 0, 0);
    __builtin_amdgcn_s_setprio(0);
    if (tt + 2 < NT) { asm volatile("s_waitcnt vmcnt(4)" ::: "memory"); }
    else             { asm volatile("s_waitcnt vmcnt(0)" ::: "memory"); }
    __builtin_amdgcn_s_barrier();
  }
#undef STAGE_A
#undef STAGE_B

  // epilogue: C/D layout col=lane&15, row=(lane>>4)*4+reg
#pragma unroll
  for (int mi = 0; mi < 8; mi++) {
#pragma unroll
    for (int ni = 0; ni < 4; ni++) {
      int col = n0 + wn * 64 + ni * 16 + r15;
      int row0 = m0 + wm * 128 + mi * 16 + q * 4;
#pragma unroll
      for (int r = 0; r < 4; r++) {
        float v = acc[mi][ni][r];
        int row = row0 + r;
        if constexpr (MODE == 2) {
          if (col < Nreal && v > TAU) {
            int p = atomicAdd(&cand_cnt[row], 1);
            if (p < CAP) {
              cand_s[row * CAP + p] = v;
              cand_i[row * CAP + p] = col;
            }
          }
        } else {
          v += bias[col];
          if constexpr (RELU) v = fmaxf(v, 0.f);
          C16[(size_t)row * ldc + col] = (f16)v;
        }
      }
    }
  }
}

// ---------------- query LN + nan_to_num + L2 normalize (f64), outputs qn64 + qn16 ----------------
__global__ __launch_bounds__(256) void ln_query(const float* __restrict__ qraw,
                                                const float* __restrict__ g, const float* __restrict__ b,
                                                double* __restrict__ qn64, f16* __restrict__ qn16) {
  int row = blockIdx.x, t = threadIdx.x;
  __shared__ double red[4];
  const float* x = qraw + (size_t)row * EDIM;
  float v[12];
  double s = 0.0;
#pragma unroll
  for (int i = 0; i < 12; i++) {
    v[i] = x[t + 256 * i];
    s += (double)v[i];
  }
  double mu = bredd(s, red) / (double)EDIM;
  double s2 = 0.0;
#pragma unroll
  for (int i = 0; i < 12; i++) {
    double d = (double)v[i] - mu;
    s2 += d * d;
  }
  double var = bredd(s2, red) / (double)EDIM;
  double rstd = 1.0 / sqrt(var + 1e-5);
  double y[12];
  double n2 = 0.0;
#pragma unroll
  for (int i = 0; i < 12; i++) {
    int e = t + 256 * i;
    double yy = ((double)v[i] - mu) * rstd * (double)g[e] + (double)b[e];
    if (isnan(yy)) yy = 0.0;
    else if (isinf(yy)) yy = (yy > 0.0) ? 1.0 : -1.0;
    y[i] = yy;
    n2 += yy * yy;
  }
  n2 = bredd(n2, red);
  double inv = 1.0 / fmax(sqrt(n2), 1e-12);
#pragma unroll
  for (int i = 0; i < 12; i++) {
    int e = t + 256 * i;
    double qv = y[i] * inv;
    qn64[(size_t)row * EDIM + e] = qv;
    qn16[(size_t)row * EDIM + e] = (f16)(float)qv;
  }
}

// ---------------- LN over 256, f16 output at (ldc, col_off) ----------------
__global__ __launch_bounds__(256) void ln_small(const float* __restrict__ in,
                                                const float* __restrict__ g, const float* __restrict__ b,
                                                f16* __restrict__ out16, int ldc, int col_off) {
  int row = blockIdx.x, t = threadIdx.x;
  __shared__ float red[4];
  float x = in[(size_t)row * 256 + t];
  float mu = bredf(x, red) * (1.f / 256.f);
  float d = x - mu;
  float var = bredf(d * d, red) * (1.f / 256.f);
  float rs = 1.f / sqrtf(var + 1e-5f);
  float y = d * rs * g[t] + b[t];
  out16[(size_t)row * ldc + col_off + t] = (f16)y;
}

// ---------------- top-k finalize: bitonic sort candidates, f64 rescore top-16, emit top-10 ----------------
__global__ __launch_bounds__(256) void topk_finalize(const float* __restrict__ cand_s,
                                                     const int* __restrict__ cand_i,
                                                     const int* __restrict__ cand_cnt,
                                                     const double* __restrict__ qn64,
                                                     const float* __restrict__ keys,
                                                     const double* __restrict__ inv_norm,
                                                     int* __restrict__ topk) {
  __shared__ float ss[256];
  __shared__ int si[256];
  __shared__ double rs[16];
  int b = blockIdx.x, t = threadIdx.x;
  int n = cand_cnt[b];
  if (n > CAP) n = CAP;
  if (t < n) {
    ss[t] = cand_s[b * CAP + t];
    si[t] = cand_i[b * CAP + t];
  } else {
    ss[t] = -1e30f;
    si[t] = 0x7fffffff;
  }
  __syncthreads();
  for (int k = 2; k <= 256; k <<= 1) {
    for (int j = k >> 1; j > 0; j >>= 1) {
      int ixj = t ^ j;
      if (ixj > t) {
        float s1 = ss[t], s2 = ss[ixj];
        int i1 = si[t], i2 = si[ixj];
        bool first = (s1 > s2) || (s1 == s2 && i1 < i2);  // t-elem should precede
        bool up = ((t & k) == 0);
        if (up != first) {
          ss[t] = s2; si[t] = i2;
          ss[ixj] = s1; si[ixj] = i1;
        }
      }
      __syncthreads();
    }
  }
  // f64 rescore of approx-top-16
  int wv = t >> 6, lane = t & 63;
  const double* q = qn64 + (size_t)b * EDIM;
  for (int j = wv; j < 16; j += 4) {
    int nidx = si[j];
    double acc = 0.0;
    if (nidx < N_KEYS) {
      const float* kr = keys + (size_t)nidx * EDIM;
      for (int e = lane; e < EDIM; e += 64) acc += q[e] * (double)kr[e];
      acc = wredd(acc);
      acc *= inv_norm[nidx];
    } else {
      acc = -1e300;
    }
    if (lane == 0) rs[j] = acc;
  }
  __syncthreads();
  if (t == 0) {
    int ord[16];
    for (int i = 0; i < 16; i++) ord[i] = i;
    for (int i = 1; i < 16; i++) {
      int o = ord[i];
      int j = i - 1;
      while (j >= 0) {
        int p = ord[j];
        bool pFirst = (rs[p] > rs[o]) || (rs[p] == rs[o] && si[p] < si[o]);
        if (pFirst) break;
        ord[j + 1] = p;
        j--;
      }
      ord[j + 1] = o;
    }
    for (int r = 0; r < 10; r++) {
      int nn = si[ord[r]];
      topk[b * 10 + r] = (nn < N_KEYS) ? nn : 0;
    }
  }
}

// ---------------- gather raw knowledge rows -> fp16 ----------------
__global__ __launch_bounds__(256) void gather_rk(const float* __restrict__ keys,
                                                 const int* __restrict__ topk,
                                                 f16* __restrict__ rk16) {
  int row = blockIdx.x, t = threadIdx.x;
  int n = topk[row];
  const float4* src = (const float4*)(keys + (size_t)n * EDIM);
  f16* dst = rk16 + (size_t)row * EDIM;
#pragma unroll
  for (int i = 0; i < 3; i++) {
    float4 v = src[t + 256 * i];
    f16x4 h = {(f16)v.x, (f16)v.y, (f16)v.z, (f16)v.w};
    *(f16x4*)(dst + (size_t)(t + 256 * i) * 4) = h;
  }
}

// ---------------- attention: per-batch softmax over K=10, H=4 heads ----------------
__global__ __launch_bounds__(256) void attention_k(const float* __restrict__ qh,
                                                   const float* __restrict__ kv,
                                                   f16* __restrict__ ctx16,
                                                   float* __restrict__ attnw) {
  int bq = blockIdx.x, t = threadIdx.x;
  int h = t >> 6, lane = t & 63;
  __shared__ float wsm[4][10];
  float q = qh[(size_t)bq * 256 + h * 64 + lane];
  const float* kvb = kv + (size_t)bq * 10 * 512;
  float logit[10];
#pragma unroll
  for (int k = 0; k < 10; k++) {
    float p = q * kvb[k * 512 + h * 64 + lane];
    p = wred(p);
    logit[k] = p * 0.125f;
  }
  float mx = logit[0];
#pragma unroll
  for (int k = 1; k < 10; k++) mx = fmaxf(mx, logit[k]);
  float e[10];
  float den = 0.f;
#pragma unroll
  for (int k = 0; k < 10; k++) {
    e[k] = expf(logit[k] - mx);
    den += e[k];
  }
  float inv = 1.f / den;
  float ctx = 0.f;
#pragma unroll
  for (int k = 0; k < 10; k++) {
    float w = e[k] * inv;
    if (lane == 0) wsm[h][k] = w;
    ctx += w * kvb[k * 512 + 256 + h * 64 + lane];
  }
  ctx16[(size_t)bq * 256 + h * 64 + lane] = (f16)ctx;
  __syncthreads();
  if (t < 10) {
    float s = 0.25f * (wsm[0][t] + wsm[1][t] + wsm[2][t] + wsm[3][t]);
    attnw[bq * 10 + t] = s;
  }
}

// ---------------- final head: logits = h @ ah_w2^T + b2 (N=23) ----------------
__global__ __launch_bounds__(256) void final_logits(const float* __restrict__ hhead,
                                                    const float* __restrict__ w2,
                                                    const float* __restrict__ b2,
                                                    float* __restrict__ outp) {
  __shared__ float w2s[23 * 256];
  int t = threadIdx.x;
  for (int i = t; i < 23 * 256; i += 256) w2s[i] = w2[i];
  __syncthreads();
  int r = t >> 5, a = t & 31;
  int row = blockIdx.x * 8 + r;
  if (a < 23) {
    const float* hp = hhead + (size_t)row * 256;
    float acc = b2[a];
    for (int k = 0; k < 256; k++) acc += hp[k] * w2s[a * 256 + k];
    outp[(size_t)row * 23 + a] = acc;
  }
}

// ---------------- critic value ----------------
__global__ __launch_bounds__(256) void value_k(const float* __restrict__ c2,
                                               const float* __restrict__ w3,
                                               const float* __restrict__ b3,
                                               float* __restrict__ outp) {
  int t = threadIdx.x;
  int wv = t >> 6, lane = t & 63;
  int row = blockIdx.x * 4 + wv;
  float acc = 0.f;
#pragma unroll
  for (int i = 0; i < 4; i++) acc += c2[(size_t)row * 256 + lane + 64 * i] * w3[lane + 64 * i];
  acc = wred(acc);
  if (lane == 0) outp[row] = acc + b3[0];
}

// =============================================================================
extern "C" void kernel_launch(void* const* d_in, const int* in_sizes, int n_in,
                              void* d_out, int out_size, void* d_ws, size_t ws_size,
                              hipStream_t stream) {
  (void)in_sizes; (void)n_in; (void)out_size;
  const float* state   = (const float*)d_in[0];
  const float* re_w1   = (const float*)d_in[1];
  const float* re_b1   = (const float*)d_in[2];
  const float* re_w2   = (const float*)d_in[3];
  const float* re_b2   = (const float*)d_in[4];
  const float* re_w3   = (const float*)d_in[5];
  const float* re_b3   = (const float*)d_in[6];
  const float* re_ln_g = (const float*)d_in[7];
  const float* re_ln_b = (const float*)d_in[8];
  const float* de_w1   = (const float*)d_in[9];
  const float* de_b1   = (const float*)d_in[10];
  const float* de_w2   = (const float*)d_in[11];
  const float* de_b2   = (const float*)d_in[12];
  const float* de_ln_g = (const float*)d_in[13];
  const float* de_ln_b = (const float*)d_in[14];
  const float* keys    = (const float*)d_in[15];
  const float* ad_w1   = (const float*)d_in[16];
  const float* ad_b1   = (const float*)d_in[17];
  const float* ad_w2   = (const float*)d_in[18];
  const float* ad_b2   = (const float*)d_in[19];
  const float* ad_ln_g = (const float*)d_in[20];
  const float* ad_ln_b = (const float*)d_in[21];
  const float* in_proj_w = (const float*)d_in[22];
  const float* in_proj_b = (const float*)d_in[23];
  const float* out_w   = (const float*)d_in[24];
  const float* out_b   = (const float*)d_in[25];
  const float* ah_w1   = (const float*)d_in[26];
  const float* ah_b1   = (const float*)d_in[27];
  const float* ah_w2   = (const float*)d_in[28];
  const float* ah_b2   = (const float*)d_in[29];
  const float* cr_w1   = (const float*)d_in[30];
  const float* cr_b1   = (const float*)d_in[31];
  const float* cr_w2   = (const float*)d_in[32];
  const float* cr_b2   = (const float*)d_in[33];
  const float* cr_w3   = (const float*)d_in[34];
  const float* cr_b3   = (const float*)d_in[35];

  char* ws = (char*)d_ws;
  size_t off = 0;
  auto alloc = [&](size_t bytes) {
    size_t p = off;
    off += (bytes + 511) & ~(size_t)511;
    return p;
  };
  // big union region: kn16 (phase 1) aliased with adapter buffers (phase 2)
  size_t UNION = alloc((size_t)N_KEYS_P * EDIM * 2);  // 307.5 MB
  size_t O_INV   = alloc((size_t)N_KEYS_P * 8);
  size_t O_QN64  = alloc((size_t)BATCH * EDIM * 8);
  size_t O_QN16  = alloc((size_t)BATCH * EDIM * 2);
  size_t O_QRAW  = alloc((size_t)BATCH * EDIM * 4);
  size_t O_H1    = alloc((size_t)BATCH * 512 * 4);
  size_t O_H2    = alloc((size_t)BATCH * 512 * 4);
  size_t O_DBUF  = alloc((size_t)BATCH * 256 * 4);
  size_t O_DE2   = alloc((size_t)BATCH * 256 * 4);
  size_t O_C1    = alloc((size_t)BATCH * 256 * 4);
  size_t O_C2    = alloc((size_t)BATCH * 256 * 4);
  size_t O_CS    = alloc((size_t)BATCH * CAP * 4);
  size_t O_CI    = alloc((size_t)BATCH * CAP * 4);
  size_t O_CNT   = alloc((size_t)BATCH * 4);
  size_t O_TOPK  = alloc((size_t)BATCH * 10 * 4);
  size_t O_W1    = alloc((size_t)1024 * 3072 * 2);  // ad_w1 f16
  size_t O_W2    = alloc((size_t)256 * 1024 * 2);   // ad_w2 f16
  size_t O_WIN   = alloc((size_t)768 * 256 * 2);    // in_proj f16
  size_t O_WOUT  = alloc((size_t)256 * 256 * 2);    // out_w f16
  size_t O_WAH1  = alloc((size_t)256 * 512 * 2);    // ah_w1 f16
  size_t O_COMB  = alloc((size_t)BATCH * 512 * 2);  // combined f16
  size_t O_QH    = alloc((size_t)BATCH * 256 * 4);
  size_t O_CTX   = alloc((size_t)BATCH * 256 * 2);
  size_t O_HH    = alloc((size_t)BATCH * 256 * 4);
  if (ws_size < off) return;  // workspace too small; fail loudly via absmax

  // union sub-layout
  f16*   kn16      = (f16*)(ws + UNION);
  f16*   rk16      = (f16*)(ws + UNION);                      // after scores
  f16*   a1_16     = (f16*)(ws + UNION + 125829120ULL);
  float* a2_32     = (float*)(ws + UNION + 167772160ULL);
  f16*   compact16 = (f16*)(ws + UNION + 188743680ULL);
  float* kv32      = (float*)(ws + UNION + 199229440ULL);

  double* inv64    = (double*)(ws + O_INV);
  double* qn64     = (double*)(ws + O_QN64);
  f16*    qn16     = (f16*)(ws + O_QN16);
  float*  qraw     = (float*)(ws + O_QRAW);
  float*  h1       = (float*)(ws + O_H1);
  float*  h2       = (float*)(ws + O_H2);
  float*  dbuf     = (float*)(ws + O_DBUF);
  float*  de2      = (float*)(ws + O_DE2);
  float*  c1       = (float*)(ws + O_C1);
  float*  c2       = (float*)(ws + O_C2);
  float*  cand_s   = (float*)(ws + O_CS);
  int*    cand_i   = (int*)(ws + O_CI);
  int*    cand_cnt = (int*)(ws + O_CNT);
  int*    topk     = (int*)(ws + O_TOPK);
  f16*    adw1_16  = (f16*)(ws + O_W1);
  f16*    adw2_16  = (f16*)(ws + O_W2);
  f16*    inproj16 = (f16*)(ws + O_WIN);
  f16*    outw16   = (f16*)(ws + O_WOUT);
  f16*    ahw1_16  = (f16*)(ws + O_WAH1);
  f16*    comb16   = (f16*)(ws + O_COMB);
  float*  qh32     = (float*)(ws + O_QH);
  f16*    ctx16    = (f16*)(ws + O_CTX);
  float*  hhead    = (float*)(ws + O_HH);

  float* out_logits = (float*)d_out;
  float* out_attnw  = (float*)d_out + 2048 * 23;
  float* out_value  = (float*)d_out + 2048 * 23 + 2048 * 10;

  hipMemsetAsync(cand_cnt, 0, BATCH * 4, stream);

  // weight conversions
  cvt_f16<<<(1024 * 3072 + 255) / 256, 256, 0, stream>>>(ad_w1, adw1_16, 1024 * 3072);
  cvt_f16<<<(256 * 1024 + 255) / 256, 256, 0, stream>>>(ad_w2, adw2_16, 256 * 1024);
  cvt_f16<<<(768 * 256 + 255) / 256, 256, 0, stream>>>(in_proj_w, inproj16, 768 * 256);
  cvt_f16<<<(256 * 256 + 255) / 256, 256, 0, stream>>>(out_w, outw16, 256 * 256);
  cvt_f16<<<(256 * 512 + 255) / 256, 256, 0, stream>>>(ah_w1, ahw1_16, 256 * 512);

  // key norms + fp16 normalized keys
  rownorm_keys<<<N_KEYS_P, 256, 0, stream>>>(keys, kn16, inv64);

  // state paths (fp32)
  gemm_f32<1, 1><<<dim3(32, 8), 256, 0, stream>>>(state, 115, re_w1, re_b1, h1, 512, 115);
  gemm_f32<1, 1><<<dim3(32, 8), 256, 0, stream>>>(h1, 512, re_w2, re_b2, h2, 512, 512);
  gemm_f32<1, 0><<<dim3(32, 48), 256, 0, stream>>>(h2, 512, re_w3, re_b3, qraw, 3072, 512);
  gemm_f32<0, 1><<<dim3(32, 4), 256, 0, stream>>>(state, 115, de_w1, de_b1, dbuf, 256, 115);
  gemm_f32<0, 0><<<dim3(32, 4), 256, 0, stream>>>(dbuf, 256, de_w2, de_b2, de2, 256, 256);
  gemm_f32<0, 1><<<dim3(32, 4), 256, 0, stream>>>(state, 115, cr_w1, cr_b1, c1, 256, 115);
  gemm_f32<0, 1><<<dim3(32, 4), 256, 0, stream>>>(c1, 256, cr_w2, cr_b2, c2, 256, 256);

  ln_query<<<BATCH, 256, 0, stream>>>(qraw, re_ln_g, re_ln_b, qn64, qn16);
  ln_small<<<BATCH, 256, 0, stream>>>(de2, de_ln_g, de_ln_b, comb16, 512, 0);  // agent -> combined[:,0:256]

  // scores + threshold candidates: 256^2 8-phase kernel.
  // grid (8,196): 196*256 = 50176 cols; cols >= 50048 read in-workspace garbage,
  // discarded by the col < Nreal guard (column-independent MFMA math).
  gemm256<2, 0><<<dim3(8, 196), 512, 0, stream>>>(qn16, EDIM, kn16, nullptr, nullptr, 0,
                                                  EDIM, N_KEYS, cand_s, cand_i, cand_cnt);
  topk_finalize<<<BATCH, 256, 0, stream>>>(cand_s, cand_i, cand_cnt, qn64, keys, inv64, topk);
  gather_rk<<<20480, 256, 0, stream>>>(keys, topk, rk16);

  // adapter (GEMM1 on the 256^2 8-phase kernel: 20480x1024x3072)
  gemm256<1, 1><<<dim3(80, 4), 512, 0, stream>>>(rk16, EDIM, adw1_16, ad_b1, a1_16, 1024,
                                                 EDIM, 0, nullptr, nullptr, nullptr);
  gemm_f16k<0, 0><<<dim3(160, 2), 256, 0, stream>>>(a1_16, 1024, adw2_16, ad_b2, a2_32, nullptr,
                                                    256, 0, 1024, 0, nullptr, nullptr, nullptr);
  ln_small<<<20480, 256, 0, stream>>>(a2_32, ad_ln_g, ad_ln_b, compact16, 256, 0);

  // attention projections
  gemm_f16k<0, 0><<<dim3(160, 4), 256, 0, stream>>>(compact16, 256, inproj16 + 256 * 256,
                                                    in_proj_b + 256, kv32, nullptr,
                                                    512, 0, 256, 0, nullptr, nullptr, nullptr);
  gemm_f16k<0, 0><<<dim3(16, 2), 256, 0, stream>>>(comb16, 512, inproj16, in_proj_b, qh32, nullptr,
                                                   256, 0, 256, 0, nullptr, nullptr, nullptr);
  attention_k<<<BATCH, 256, 0, stream>>>(qh32, kv32, ctx16, out_attnw);
  gemm_f16k<1, 0><<<dim3(16, 2), 256, 0, stream>>>(ctx16, 256, outw16, out_b, nullptr, comb16,
                                                   512, 256, 256, 0, nullptr, nullptr, nullptr);
  gemm_f16k<0, 1><<<dim3(16, 2), 256, 0, stream>>>(comb16, 512, ahw1_16, ah_b1, hhead, nullptr,
                                                   256, 0, 512, 0, nullptr, nullptr, nullptr);
  final_logits<<<BATCH / 8, 256, 0, stream>>>(hhead, ah_w2, ah_b2, out_logits);
  value_k<<<BATCH / 4, 256, 0, stream>>>(c2, cr_w3, cr_b3, out_value);
}